// Round 15
// baseline (416.224 us; speedup 1.0000x reference)
//
#include <hip/hip_runtime.h>

#define DEV __device__ __forceinline__

using f32x4  = __attribute__((ext_vector_type(4))) float;
using bf16x8 = __attribute__((ext_vector_type(8))) __bf16;
using u16x4  = __attribute__((ext_vector_type(4))) unsigned short;

constexpr int S_ = 2048, D_ = 1024, H_ = 16, DK_ = 64;
constexpr float LOG2E_ = 1.44269504f;
constexpr float M2_ = 8.0f * 1.44269504f;     // fixed shift in exp2 domain
constexpr float C1_ = 0.125f * 1.44269504f;   // score scale * log2e

DEV unsigned short f2bf(float x) {
  unsigned int u = __float_as_uint(x);
  u += 0x7fffu + ((u >> 16) & 1u);
  return (unsigned short)(u >> 16);
}

DEV float bf2f(unsigned short u) {
  return __uint_as_float((unsigned int)u << 16);
}

DEV void gload_lds16(const void* g, void* l) {
  __builtin_amdgcn_global_load_lds(
      (__attribute__((address_space(1))) void*)g,
      (__attribute__((address_space(3))) void*)l, 16, 0, 0);
}

DEV f32x4 mfma_bf16(bf16x8 a, bf16x8 b, f32x4 c) {
  return __builtin_amdgcn_mfma_f32_16x16x32_bf16(a, b, c, 0, 0, 0);
}

// ---------------- elementwise converters / packers ----------------

__global__ __launch_bounds__(256) void qkv_to_bf16(
    const float* __restrict__ q, const float* __restrict__ k,
    const float* __restrict__ v, unsigned short* __restrict__ dst) {
  int seg = blockIdx.x >> 12;
  int j = ((blockIdx.x & 4095) << 8) + threadIdx.x;
  const float* s = seg == 0 ? q : (seg == 1 ? k : v);
  unsigned short* d = dst + (size_t)seg * 4194304;
  f32x4 val = *(const f32x4*)(s + (size_t)j * 4);
  u16x4 o;
  o[0] = f2bf(val[0]); o[1] = f2bf(val[1]); o[2] = f2bf(val[2]); o[3] = f2bf(val[3]);
  *(u16x4*)(d + (size_t)j * 4) = o;
}

// pm2 = (mask ? -1e9 : prior) * log2e, stored bf16
__global__ __launch_bounds__(256) void make_pm2(
    const int* __restrict__ mask, const float* __restrict__ prior,
    unsigned short* __restrict__ pm2, int n4) {
  int i = blockIdx.x * 256 + threadIdx.x;
  if (i >= n4) return;
  const int* m = mask + (size_t)i * 4;
  f32x4 p = *(const f32x4*)(prior + (size_t)i * 4);
  u16x4 o;
#pragma unroll
  for (int j = 0; j < 4; ++j)
    o[j] = f2bf(m[j] ? -1.44269504e9f : p[j] * LOG2E_);
  *(u16x4*)(pm2 + (size_t)i * 4) = o;
}

// WT[n][d] = W[h][d][kk], n = h*64+kk  -- Wq and Wk fused
__global__ __launch_bounds__(256) void pack_wqk2(
    const float* __restrict__ Wq, const float* __restrict__ Wk,
    unsigned short* __restrict__ WT) {
  int seg = blockIdx.x >> 12;
  int i = ((blockIdx.x & 4095) << 8) + threadIdx.x;
  const float* W = seg ? Wk : Wq;
  int d = i & 1023, n = i >> 10;
  int hh = n >> 6, kk = n & 63;
  WT[(size_t)seg * 1048576 + i] = f2bf(W[((size_t)hh * 1024 + d) * 64 + kk]);
}

__global__ __launch_bounds__(256) void pack_wv(
    const float* __restrict__ W, unsigned short* __restrict__ WT) {
  int i = blockIdx.x * 256 + threadIdx.x;
  int d = i & 1023, kk = i >> 10;
  WT[i] = f2bf(W[(size_t)d * 64 + kk]);
}

__global__ __launch_bounds__(256) void pack_wh(
    const float* __restrict__ W, unsigned short* __restrict__ WT) {
  int i = blockIdx.x * 256 + threadIdx.x;
  int k = i & 63, n = i >> 6;
  WT[i] = f2bf(W[(size_t)k * 1024 + n]);
}

// hbar = mean over 16 heads (heads already softmax-normalized)
__global__ __launch_bounds__(256) void mean_heads(
    const float* __restrict__ hp, unsigned short* __restrict__ hbar) {
  int i = blockIdx.x * 256 + threadIdx.x;  // 4096*64
  int kk = i & 63, m = i >> 6;
  int b = m >> 11, s = m & 2047;
  float acc = 0.f;
#pragma unroll
  for (int hh = 0; hh < 16; ++hh)
    acc += hp[(((size_t)b * 16 + hh) * 2048 + s) * 64 + kk];
  hbar[i] = f2bf(acc * 0.0625f);
}

// ---------------- bf16 MFMA GEMM, C = A * BT^T (+bias), custom epilogues ----
// MODE 0: bf16 out at [b][h][s][kk]  (m=b*2048+s, n=h*64+kk)  (qs/ks)
// MODE 1: bf16 out at [b][n][t]      (m=b*2048+t, N=64)       (vsT)
// MODE 2: f32 out at [m][n]          (out projection, no bias)

template <int BN, int MODE>
__global__ __launch_bounds__(256) void gemm_bt(
    const unsigned short* __restrict__ A, const unsigned short* __restrict__ BT,
    const float* __restrict__ bias, void* __restrict__ outp, int M, int N, int K) {
  constexpr int BM = 128, BK = 64;
  constexpr int NWC = BN / 64;
  constexpr int NWR = 4 / NWC;
  constexpr int WTM = BM / NWR;
  constexpr int MI = WTM / 16;
  constexpr int NI = 4;
  __shared__ unsigned short ldsA[BM * BK];
  __shared__ unsigned short ldsB[BN * BK];
  const int tid = threadIdx.x;
  const int wave = tid >> 6, lane = tid & 63;
  const int g = lane >> 4, l4 = lane & 15;
  const int m0 = blockIdx.x * BM, n0 = blockIdx.y * BN;
  const int wr = wave / NWC, wc = wave % NWC;
  const int r8 = lane >> 3, s8 = lane & 7;
  f32x4 acc[MI][NI];
#pragma unroll
  for (int mi = 0; mi < MI; ++mi)
#pragma unroll
    for (int ni = 0; ni < NI; ++ni) acc[mi][ni] = {0.f, 0.f, 0.f, 0.f};

  for (int k0 = 0; k0 < K; k0 += BK) {
    __syncthreads();
#pragma unroll
    for (int j = 0; j < 4; ++j) {
      int c = wave * 4 + j;
      int row = c * 8 + r8;
      int slot = s8 ^ (row & 7);
      gload_lds16(A + (size_t)(m0 + row) * K + k0 + slot * 8, &ldsA[c * 512]);
    }
    constexpr int BCH = BN * BK / 512;
#pragma unroll
    for (int j = 0; j < BCH / 4; ++j) {
      int c = wave * (BCH / 4) + j;
      int row = c * 8 + r8;
      int slot = s8 ^ (row & 7);
      gload_lds16(BT + (size_t)(n0 + row) * K + k0 + slot * 8, &ldsB[c * 512]);
    }
    __syncthreads();
    bf16x8 af[MI][2], bfr[NI][2];
#pragma unroll
    for (int mi = 0; mi < MI; ++mi)
#pragma unroll
      for (int kss = 0; kss < 2; ++kss) {
        int row = wr * WTM + mi * 16 + l4;
        int slot = (kss * 4 + g) ^ (row & 7);
        af[mi][kss] = *(const bf16x8*)&ldsA[row * 64 + slot * 8];
      }
#pragma unroll
    for (int ni = 0; ni < NI; ++ni)
#pragma unroll
      for (int kss = 0; kss < 2; ++kss) {
        int row = wc * 64 + ni * 16 + l4;
        int slot = (kss * 4 + g) ^ (row & 7);
        bfr[ni][kss] = *(const bf16x8*)&ldsB[row * 64 + slot * 8];
      }
#pragma unroll
    for (int mi = 0; mi < MI; ++mi)
#pragma unroll
      for (int ni = 0; ni < NI; ++ni)
#pragma unroll
        for (int kss = 0; kss < 2; ++kss)
          acc[mi][ni] = mfma_bf16(af[mi][kss], bfr[ni][kss], acc[mi][ni]);
  }

#pragma unroll
  for (int mi = 0; mi < MI; ++mi)
#pragma unroll
    for (int ni = 0; ni < NI; ++ni)
#pragma unroll
      for (int r = 0; r < 4; ++r) {
        int m = m0 + wr * WTM + mi * 16 + g * 4 + r;
        int n = n0 + wc * 64 + ni * 16 + l4;
        float c = acc[mi][ni][r];
        if constexpr (MODE != 2) c += bias[n];
        if constexpr (MODE == 0) {
          int b = m >> 11, s = m & 2047, hh = n >> 6, kk = n & 63;
          ((unsigned short*)outp)[(((size_t)b * 16 + hh) * 2048 + s) * 64 + kk] = f2bf(c);
        } else if constexpr (MODE == 1) {
          int b = m >> 11, t = m & 2047;
          ((unsigned short*)outp)[((size_t)b * 64 + n) * 2048 + t] = f2bf(c);
        } else {
          ((float*)outp)[(size_t)m * N + n] = c;
        }
      }
}

// ---------------- fused attention (32 q-rows/block; barrier-free PV) -------
// Block = (bh, 32 q-rows) x full T; 512 threads = 8 waves, wave w owns
// t in [256w, 256w+256). Phase order:
//   1. QK(x2 rowsets) + blend -> p in own-wave LDS; lsum -> lds_sum
//   2. PV loop (own-wave p + prefetched V + MFMA) -- NO barrier needed
//   3. __syncthreads -> invl; PURE store stream (no MFMA competing)
//   4. partials -> dead p region -> barrier -> heads reduce
// s_setprio(1) around PV MFMA cluster (waves are phase-diverse).

__global__ __launch_bounds__(512, 2) void attn_fused1(
    const unsigned short* __restrict__ qs, const unsigned short* __restrict__ ks,
    const unsigned short* __restrict__ vsT, const unsigned short* __restrict__ pm2,
    float* __restrict__ attn_out, float* __restrict__ heads) {
  __shared__ unsigned short lds_p[8][32 * 256];  // 128 KB
  __shared__ float lds_sum[8][32];               // 1 KB

  const int tid = threadIdx.x;
  const int w = tid >> 6, lane = tid & 63;
  const int g = lane >> 4, l4 = lane & 15;
  const int blk = ((blockIdx.x & 7) << 8) + (blockIdx.x >> 3);  // bijective, 2048
  const int sblk = blk & 63, bh = blk >> 6;
  const int b = bh >> 4, h = bh & 15;
  const int tb = w << 8;  // wave's t-base (256-range)

  const unsigned short* qsb = qs + ((size_t)bh * S_ + sblk * 32) * DK_;
  const unsigned short* ksb = ks + (size_t)bh * S_ * DK_ + (size_t)tb * DK_;
  const unsigned short* pmrow0 = pm2 + ((size_t)b * S_ + sblk * 32 + l4) * S_ + tb;
  const unsigned short* pmrow1 = pmrow0 + (size_t)16 * S_;
  const unsigned short* vtb = vsT + (size_t)b * DK_ * S_ + tb;

  // Q fragments for both row-sets
  bf16x8 aq0[2], aq1[2];
#pragma unroll
  for (int kss = 0; kss < 2; ++kss) {
    aq0[kss] = *(const bf16x8*)(qsb + (size_t)l4 * DK_ + (kss * 4 + g) * 8);
    aq1[kss] = *(const bf16x8*)(qsb + (size_t)(16 + l4) * DK_ + (kss * 4 + g) * 8);
  }

  char* pbase = (char*)&lds_p[w][0];  // 16 KB, row r at byte r*512
  const int swz = (l4 & 7) << 4;      // XOR byte bits 4..6 ((row&7)==(l4&7))

  // ---------- PHASE 1: 4 tiles of 64 t; QK(x2) + blend -> p in LDS ----------
  float lsum0 = 0.f, lsum1 = 0.f;
  u16x4 pc0[2][4], pc1[2][4];   // pm bf16, 2-deep ring
#pragma unroll
  for (int d = 0; d < 2; ++d)
#pragma unroll
    for (int ct = 0; ct < 4; ++ct) {
      pc0[d][ct] = *(const u16x4*)(pmrow0 + d * 64 + ct * 16 + g * 4);
      pc1[d][ct] = *(const u16x4*)(pmrow1 + d * 64 + ct * 16 + g * 4);
    }
  bf16x8 kf[2][4][2];           // K, 1-deep ring
#pragma unroll
  for (int ct = 0; ct < 4; ++ct)
#pragma unroll
    for (int kss = 0; kss < 2; ++kss)
      kf[0][ct][kss] = *(const bf16x8*)(ksb +
          (size_t)(ct * 16 + l4) * DK_ + (kss * 4 + g) * 8);

#pragma unroll
  for (int i = 0; i < 4; ++i) {
    const int tr = i * 64;
    const int cur = i & 1, nxt = (i + 1) & 1;
    if (i + 1 < 4) {
#pragma unroll
      for (int ct = 0; ct < 4; ++ct)
#pragma unroll
        for (int kss = 0; kss < 2; ++kss)
          kf[nxt][ct][kss] = *(const bf16x8*)(ksb +
              (size_t)((i + 1) * 64 + ct * 16 + l4) * DK_ + (kss * 4 + g) * 8);
    }
#pragma unroll
    for (int ct = 0; ct < 4; ++ct) {
      f32x4 a0 = {0.f, 0.f, 0.f, 0.f}, a1 = {0.f, 0.f, 0.f, 0.f};
      __builtin_amdgcn_s_setprio(1);
#pragma unroll
      for (int kss = 0; kss < 2; ++kss) {
        a0 = mfma_bf16(kf[cur][ct][kss], aq0[kss], a0);
        a1 = mfma_bf16(kf[cur][ct][kss], aq1[kss], a1);
      }
      __builtin_amdgcn_s_setprio(0);
      u16x4 pb0, pb1;
#pragma unroll
      for (int r = 0; r < 4; ++r) {
        {
          float pmv = bf2f(pc0[cur][ct][r]);
          float sc2 = a0[r] * C1_;
          float e = __builtin_amdgcn_exp2f(-(sc2 + pmv));
          float z = __builtin_amdgcn_rcpf(1.f + e);
          float p = __builtin_amdgcn_exp2f(pmv + z * (sc2 - pmv) - M2_);
          lsum0 += p;
          pb0[r] = f2bf(p);
        }
        {
          float pmv = bf2f(pc1[cur][ct][r]);
          float sc2 = a1[r] * C1_;
          float e = __builtin_amdgcn_exp2f(-(sc2 + pmv));
          float z = __builtin_amdgcn_rcpf(1.f + e);
          float p = __builtin_amdgcn_exp2f(pmv + z * (sc2 - pmv) - M2_);
          lsum1 += p;
          pb1[r] = f2bf(p);
        }
      }
      const int toff = ((tr + ct * 16 + g * 4) * 2) ^ swz;
      *(u16x4*)(pbase + (size_t)l4 * 512 + toff) = pb0;
      *(u16x4*)(pbase + (size_t)(16 + l4) * 512 + toff) = pb1;
    }
    if (i + 2 < 4) {
#pragma unroll
      for (int ct = 0; ct < 4; ++ct) {
        pc0[cur][ct] = *(const u16x4*)(pmrow0 + (i + 2) * 64 + ct * 16 + g * 4);
        pc1[cur][ct] = *(const u16x4*)(pmrow1 + (i + 2) * 64 + ct * 16 + g * 4);
      }
    }
  }
  lsum0 += __shfl_xor(lsum0, 16);
  lsum0 += __shfl_xor(lsum0, 32);
  lsum1 += __shfl_xor(lsum1, 16);
  lsum1 += __shfl_xor(lsum1, 32);
  if (g == 0) {
    lds_sum[w][l4] = lsum0;
    lds_sum[w][16 + l4] = lsum1;
  }

  // ---------- PV loop: own-wave p only -> NO barrier ----------
  f32x4 acc0_[4], acc1_[4];
#pragma unroll
  for (int ni = 0; ni < 4; ++ni) {
    acc0_[ni] = {0.f, 0.f, 0.f, 0.f};
    acc1_[ni] = {0.f, 0.f, 0.f, 0.f};
  }

  bf16x8 vf[2][4];  // V, 1-step ring
#pragma unroll
  for (int ni = 0; ni < 4; ++ni)
    vf[0][ni] = *(const bf16x8*)(vtb + (size_t)(ni * 16 + l4) * S_ + g * 8);

#pragma unroll
  for (int st = 0; st < 8; ++st) {
    const int t0 = st * 32;
    const int cur = st & 1, nxt = (st + 1) & 1;
    if (st + 1 < 8) {
#pragma unroll
      for (int ni = 0; ni < 4; ++ni)
        vf[nxt][ni] = *(const bf16x8*)(vtb +
            (size_t)(ni * 16 + l4) * S_ + t0 + 32 + g * 8);
    }
    const int toff = ((t0 + g * 8) * 2) ^ swz;
    bf16x8 pa0 = *(const bf16x8*)(pbase + (size_t)l4 * 512 + toff);
    bf16x8 pa1 = *(const bf16x8*)(pbase + (size_t)(16 + l4) * 512 + toff);
    __builtin_amdgcn_s_setprio(1);
#pragma unroll
    for (int ni = 0; ni < 4; ++ni) {
      acc0_[ni] = mfma_bf16(pa0, vf[cur][ni], acc0_[ni]);
      acc1_[ni] = mfma_bf16(pa1, vf[cur][ni], acc1_[ni]);
    }
    __builtin_amdgcn_s_setprio(0);
  }

  __syncthreads();  // guards lds_sum (invl) block-wide

  // ---------- pure store stream: attn = f32(p) * invl ----------
  float invl0, invl1;
  {
    float s0 = 0.f, s1 = 0.f;
#pragma unroll
    for (int wv = 0; wv < 8; ++wv) {
      s0 += lds_sum[wv][l4];
      s1 += lds_sum[wv][16 + l4];
    }
    invl0 = 1.f / s0;
    invl1 = 1.f / s1;
  }

  float* attrow0 = attn_out +
      (((size_t)b * S_ + sblk * 32 + l4) * H_ + h) * S_ + tb;
  float* attrow1 = attrow0 + (size_t)16 * H_ * S_;

#pragma unroll
  for (int st = 0; st < 8; ++st) {
    const int t0 = st * 32;
    const int toff = ((t0 + g * 8) * 2) ^ swz;
    bf16x8 pa0 = *(const bf16x8*)(pbase + (size_t)l4 * 512 + toff);
    bf16x8 pa1 = *(const bf16x8*)(pbase + (size_t)(16 + l4) * 512 + toff);
    f32x4 a0, a1, a2, a3;
#pragma unroll
    for (int j = 0; j < 4; ++j) {
      a0[j] = (float)pa0[j] * invl0;
      a1[j] = (float)pa0[4 + j] * invl0;
      a2[j] = (float)pa1[j] * invl1;
      a3[j] = (float)pa1[4 + j] * invl1;
    }
    *(f32x4*)(attrow0 + t0 + g * 8) = a0;
    *(f32x4*)(attrow0 + t0 + g * 8 + 4) = a1;
    *(f32x4*)(attrow1 + t0 + g * 8) = a2;
    *(f32x4*)(attrow1 + t0 + g * 8 + 4) = a3;
  }

  // raw PV partials into own (now dead) p region: [row][kk ni*16+l4] f32
  float* pr_lds = (float*)pbase;
#pragma unroll
  for (int ni = 0; ni < 4; ++ni)
#pragma unroll
    for (int r = 0; r < 4; ++r) {
      pr_lds[(g * 4 + r) * 64 + ni * 16 + l4] = acc0_[ni][r];
      pr_lds[(16 + g * 4 + r) * 64 + ni * 16 + l4] = acc1_[ni][r];
    }

  __syncthreads();

  // 8-way reduce + per-row iv; coalesced heads write (512 thr x f32x4)
  {
    int row = tid >> 4;  // element e = tid*4 -> row = e/64, rows 0..31
    float sv = 0.f;
#pragma unroll
    for (int wv = 0; wv < 8; ++wv) sv += lds_sum[wv][row];
    float iv = 1.f / sv;
    f32x4 s4 = {0.f, 0.f, 0.f, 0.f};
#pragma unroll
    for (int wv = 0; wv < 8; ++wv) {
      f32x4 part = *(const f32x4*)((char*)&lds_p[wv][0] + tid * 16);
      s4[0] += part[0]; s4[1] += part[1]; s4[2] += part[2]; s4[3] += part[3];
    }
    s4[0] *= iv; s4[1] *= iv; s4[2] *= iv; s4[3] *= iv;
    *(f32x4*)(heads + ((size_t)bh * S_ + sblk * 32) * 64 + tid * 4) = s4;
  }
}

// ---------------- launch ----------------

extern "C" void kernel_launch(void* const* d_in, const int* in_sizes, int n_in,
                              void* d_out, int out_size, void* d_ws, size_t ws_size,
                              hipStream_t stream) {
  (void)in_sizes; (void)n_in; (void)out_size; (void)ws_size;
  const float* q     = (const float*)d_in[0];
  const float* k     = (const float*)d_in[1];
  const float* v     = (const float*)d_in[2];
  const int*   mask  = (const int*)d_in[3];
  const float* prior = (const float*)d_in[4];
  const float* Wq    = (const float*)d_in[5];
  const float* bq    = (const float*)d_in[6];
  const float* Wk    = (const float*)d_in[7];
  const float* bk    = (const float*)d_in[8];
  const float* Wv    = (const float*)d_in[9];
  const float* bv    = (const float*)d_in[10];
  const float* Wh    = (const float*)d_in[11];

  float* out  = (float*)d_out;
  float* attn = out + (size_t)4096 * 1024;

  char* ws = (char*)d_ws;
  // region [0, 25.2MB): q_bf/k_bf/v_bf during converts+gemms, then pm2 (16.7MB)
  unsigned short* q_bf  = (unsigned short*)(ws + 0);          // 3x 8MB
  unsigned short* pm2   = (unsigned short*)(ws + 0);          // 16.7MB (after gemms)
  float*          heads = (float*)(ws + 33554432);            // 16.7MB
  unsigned short* WqT   = (unsigned short*)(ws + 50331648);   // 4MB (Wq+Wk)
  unsigned short* WvT   = (unsigned short*)(ws + 54525952);   // 128KB
  unsigned short* WhT   = (unsigned short*)(ws + 54657024);   // 128KB
  unsigned short* qs_bf = (unsigned short*)(ws + 54788096);   // 8MB
  unsigned short* ks_bf = (unsigned short*)(ws + 63176704);   // 8MB
  unsigned short* vsT   = (unsigned short*)(ws + 71565312);   // 512KB
  unsigned short* hbar  = (unsigned short*)(ws + 72089600);   // 512KB

  qkv_to_bf16<<<12288, 256, 0, stream>>>(q, k, v, q_bf);
  pack_wqk2<<<8192, 256, 0, stream>>>(Wq, Wk, WqT);
  pack_wv<<<256, 256, 0, stream>>>(Wv, WvT);
  pack_wh<<<256, 256, 0, stream>>>(Wh, WhT);

  gemm_bt<128, 0><<<dim3(32, 8), 256, 0, stream>>>(q_bf, WqT, bq, qs_bf, 4096, 1024, 1024);
  gemm_bt<128, 0><<<dim3(32, 8), 256, 0, stream>>>(q_bf + 4194304, WqT + 1048576, bk, ks_bf, 4096, 1024, 1024);
  gemm_bt<64, 1><<<dim3(32, 1), 256, 0, stream>>>(q_bf + 8388608, WvT, bv, vsT, 4096, 64, 1024);

  make_pm2<<<8192, 256, 0, stream>>>(mask, prior, pm2, 2097152);

  attn_fused1<<<2048, 512, 0, stream>>>(qs_bf, ks_bf, vsT, pm2, attn, heads);

  mean_heads<<<1024, 256, 0, stream>>>(heads, hbar);
  gemm_bt<128, 2><<<dim3(32, 8), 256, 0, stream>>>(hbar, WhT, nullptr, out, 4096, 1024, 64);
}

// Round 17
// 373.226 us; speedup vs baseline: 1.1152x; 1.1152x over previous
//
#include <hip/hip_runtime.h>

#define DEV __device__ __forceinline__

using f32x4  = __attribute__((ext_vector_type(4))) float;
using int4v  = __attribute__((ext_vector_type(4))) int;
using bf16x8 = __attribute__((ext_vector_type(8))) __bf16;
using u16x4  = __attribute__((ext_vector_type(4))) unsigned short;

constexpr int S_ = 2048, D_ = 1024, H_ = 16, DK_ = 64;
constexpr float LOG2E_ = 1.44269504f;
constexpr float M2_ = 8.0f * 1.44269504f;     // fixed shift in exp2 domain
constexpr float C1_ = 0.125f * 1.44269504f;   // score scale * log2e

DEV unsigned short f2bf(float x) {
  unsigned int u = __float_as_uint(x);
  u += 0x7fffu + ((u >> 16) & 1u);
  return (unsigned short)(u >> 16);
}

DEV float bf2f(unsigned short u) {
  return __uint_as_float((unsigned int)u << 16);
}

DEV void gload_lds16(const void* g, void* l) {
  __builtin_amdgcn_global_load_lds(
      (__attribute__((address_space(1))) void*)g,
      (__attribute__((address_space(3))) void*)l, 16, 0, 0);
}

DEV f32x4 mfma_bf16(bf16x8 a, bf16x8 b, f32x4 c) {
  return __builtin_amdgcn_mfma_f32_16x16x32_bf16(a, b, c, 0, 0, 0);
}

// ---------------- elementwise converters / packers ----------------

__global__ __launch_bounds__(256) void qkv_to_bf16(
    const float* __restrict__ q, const float* __restrict__ k,
    const float* __restrict__ v, unsigned short* __restrict__ dst) {
  int seg = blockIdx.x >> 12;
  int j = ((blockIdx.x & 4095) << 8) + threadIdx.x;
  const float* s = seg == 0 ? q : (seg == 1 ? k : v);
  unsigned short* d = dst + (size_t)seg * 4194304;
  f32x4 val = *(const f32x4*)(s + (size_t)j * 4);
  u16x4 o;
  o[0] = f2bf(val[0]); o[1] = f2bf(val[1]); o[2] = f2bf(val[2]); o[3] = f2bf(val[3]);
  *(u16x4*)(d + (size_t)j * 4) = o;
}

// pm3: chunked coalesced layout for the attn kernel.
// chunk cidx = b*16384 + sblk*256 + w*32 + i*8 + ct*2 + rs  (512B each, lane*8)
// element (lane=(g,l4), r) = (mask ? -1e9 : prior)[b][sblk*32+rs*16+l4]
//                                            [w*256+i*64+ct*16+g*4+r] * log2e
__global__ __launch_bounds__(256) void make_pm3(
    const int* __restrict__ mask, const float* __restrict__ prior,
    unsigned short* __restrict__ pm3) {
  int tid = blockIdx.x * 256 + threadIdx.x;  // 2.1M threads, one u16x4 each
  int lane = tid & 63, cidx = tid >> 6;
  int rs = cidx & 1, ct = (cidx >> 1) & 3, i = (cidx >> 3) & 3;
  int w = (cidx >> 5) & 7, sblk = (cidx >> 8) & 63, b = cidx >> 14;
  int g = lane >> 4, l4 = lane & 15;
  int s = sblk * 32 + rs * 16 + l4;
  int t = w * 256 + i * 64 + ct * 16 + g * 4;
  size_t off = ((size_t)b * S_ + s) * S_ + t;
  int4v m = *(const int4v*)(mask + off);
  f32x4 p = *(const f32x4*)(prior + off);
  u16x4 o;
#pragma unroll
  for (int j = 0; j < 4; ++j)
    o[j] = f2bf(m[j] ? -1.44269504e9f : p[j] * LOG2E_);
  *(u16x4*)(pm3 + (size_t)tid * 4) = o;
}

// WT[n][d] = W[h][d][kk], n = h*64+kk  -- Wq and Wk fused
__global__ __launch_bounds__(256) void pack_wqk2(
    const float* __restrict__ Wq, const float* __restrict__ Wk,
    unsigned short* __restrict__ WT) {
  int seg = blockIdx.x >> 12;
  int i = ((blockIdx.x & 4095) << 8) + threadIdx.x;
  const float* W = seg ? Wk : Wq;
  int d = i & 1023, n = i >> 10;
  int hh = n >> 6, kk = n & 63;
  WT[(size_t)seg * 1048576 + i] = f2bf(W[((size_t)hh * 1024 + d) * 64 + kk]);
}

__global__ __launch_bounds__(256) void pack_wv(
    const float* __restrict__ W, unsigned short* __restrict__ WT) {
  int i = blockIdx.x * 256 + threadIdx.x;
  int d = i & 1023, kk = i >> 10;
  WT[i] = f2bf(W[(size_t)d * 64 + kk]);
}

__global__ __launch_bounds__(256) void pack_wh(
    const float* __restrict__ W, unsigned short* __restrict__ WT) {
  int i = blockIdx.x * 256 + threadIdx.x;
  int k = i & 63, n = i >> 6;
  WT[i] = f2bf(W[(size_t)k * 1024 + n]);
}

// hbar = mean over 16 heads (heads already softmax-normalized)
__global__ __launch_bounds__(256) void mean_heads(
    const float* __restrict__ hp, unsigned short* __restrict__ hbar) {
  int i = blockIdx.x * 256 + threadIdx.x;  // 4096*64
  int kk = i & 63, m = i >> 6;
  int b = m >> 11, s = m & 2047;
  float acc = 0.f;
#pragma unroll
  for (int hh = 0; hh < 16; ++hh)
    acc += hp[(((size_t)b * 16 + hh) * 2048 + s) * 64 + kk];
  hbar[i] = f2bf(acc * 0.0625f);
}

// ---------------- bf16 MFMA GEMM, C = A * BT^T (+bias), custom epilogues ----
// MODE 0: bf16 out at [b][h][s][kk]  (m=b*2048+s, n=h*64+kk)  (qs/ks)
// MODE 1: bf16 out at [b][n][t]      (m=b*2048+t, N=64)       (vsT)
// MODE 2: f32 out at [m][n]          (out projection, no bias)

template <int BN, int MODE>
__global__ __launch_bounds__(256) void gemm_bt(
    const unsigned short* __restrict__ A, const unsigned short* __restrict__ BT,
    const float* __restrict__ bias, void* __restrict__ outp, int M, int N, int K) {
  constexpr int BM = 128, BK = 64;
  constexpr int NWC = BN / 64;
  constexpr int NWR = 4 / NWC;
  constexpr int WTM = BM / NWR;
  constexpr int MI = WTM / 16;
  constexpr int NI = 4;
  __shared__ unsigned short ldsA[BM * BK];
  __shared__ unsigned short ldsB[BN * BK];
  const int tid = threadIdx.x;
  const int wave = tid >> 6, lane = tid & 63;
  const int g = lane >> 4, l4 = lane & 15;
  const int m0 = blockIdx.x * BM, n0 = blockIdx.y * BN;
  const int wr = wave / NWC, wc = wave % NWC;
  const int r8 = lane >> 3, s8 = lane & 7;
  f32x4 acc[MI][NI];
#pragma unroll
  for (int mi = 0; mi < MI; ++mi)
#pragma unroll
    for (int ni = 0; ni < NI; ++ni) acc[mi][ni] = {0.f, 0.f, 0.f, 0.f};

  for (int k0 = 0; k0 < K; k0 += BK) {
    __syncthreads();
#pragma unroll
    for (int j = 0; j < 4; ++j) {
      int c = wave * 4 + j;
      int row = c * 8 + r8;
      int slot = s8 ^ (row & 7);
      gload_lds16(A + (size_t)(m0 + row) * K + k0 + slot * 8, &ldsA[c * 512]);
    }
    constexpr int BCH = BN * BK / 512;
#pragma unroll
    for (int j = 0; j < BCH / 4; ++j) {
      int c = wave * (BCH / 4) + j;
      int row = c * 8 + r8;
      int slot = s8 ^ (row & 7);
      gload_lds16(BT + (size_t)(n0 + row) * K + k0 + slot * 8, &ldsB[c * 512]);
    }
    __syncthreads();
    bf16x8 af[MI][2], bfr[NI][2];
#pragma unroll
    for (int mi = 0; mi < MI; ++mi)
#pragma unroll
      for (int kss = 0; kss < 2; ++kss) {
        int row = wr * WTM + mi * 16 + l4;
        int slot = (kss * 4 + g) ^ (row & 7);
        af[mi][kss] = *(const bf16x8*)&ldsA[row * 64 + slot * 8];
      }
#pragma unroll
    for (int ni = 0; ni < NI; ++ni)
#pragma unroll
      for (int kss = 0; kss < 2; ++kss) {
        int row = wc * 64 + ni * 16 + l4;
        int slot = (kss * 4 + g) ^ (row & 7);
        bfr[ni][kss] = *(const bf16x8*)&ldsB[row * 64 + slot * 8];
      }
#pragma unroll
    for (int mi = 0; mi < MI; ++mi)
#pragma unroll
      for (int ni = 0; ni < NI; ++ni)
#pragma unroll
        for (int kss = 0; kss < 2; ++kss)
          acc[mi][ni] = mfma_bf16(af[mi][kss], bfr[ni][kss], acc[mi][ni]);
  }

#pragma unroll
  for (int mi = 0; mi < MI; ++mi)
#pragma unroll
    for (int ni = 0; ni < NI; ++ni)
#pragma unroll
      for (int r = 0; r < 4; ++r) {
        int m = m0 + wr * WTM + mi * 16 + g * 4 + r;
        int n = n0 + wc * 64 + ni * 16 + l4;
        float c = acc[mi][ni][r];
        if constexpr (MODE != 2) c += bias[n];
        if constexpr (MODE == 0) {
          int b = m >> 11, s = m & 2047, hh = n >> 6, kk = n & 63;
          ((unsigned short*)outp)[(((size_t)b * 16 + hh) * 2048 + s) * 64 + kk] = f2bf(c);
        } else if constexpr (MODE == 1) {
          int b = m >> 11, t = m & 2047;
          ((unsigned short*)outp)[((size_t)b * 64 + n) * 2048 + t] = f2bf(c);
        } else {
          ((float*)outp)[(size_t)m * N + n] = c;
        }
      }
}

// ---------------- fused attention (32 q-rows/block; pm3 L2-resident) -------
// R14 structure. Block decode h-INNERMOST: blk = [b|h_hi|sblk|h_lo] so the
// ~64 co-resident blocks per XCD share {8 K-panels (2MB) + pm window (1MB)
// + V (0.25MB)} <= 4MB L2 -> pm's 268MB demand becomes L2 hits.
// pm loads: one 512B fully-coalesced chunk (base + lane*8) per (i,ct,rs).
// NOTE R17 fix: wave chunk base is *32* chunks per (b,sblk,w), not 16.

__global__ __launch_bounds__(512, 2) void attn_fused1(
    const unsigned short* __restrict__ qs, const unsigned short* __restrict__ ks,
    const unsigned short* __restrict__ vsT, const unsigned short* __restrict__ pm3,
    float* __restrict__ attn_out, float* __restrict__ heads) {
  __shared__ unsigned short lds_p[8][32 * 256];  // 128 KB
  __shared__ float lds_sum[8][32];               // 1 KB

  const int tid = threadIdx.x;
  const int w = tid >> 6, lane = tid & 63;
  const int g = lane >> 4, l4 = lane & 15;
  const int blk = ((blockIdx.x & 7) << 8) + (blockIdx.x >> 3);  // bijective, 2048
  // decode: [b(1) | h_hi(1) | sblk(6) | h_lo(3)]  -- h innermost for L2 reuse
  const int b = blk >> 10;
  const int h = ((blk >> 9) & 1) * 8 + (blk & 7);
  const int sblk = (blk >> 3) & 63;
  const int bh = b * 16 + h;
  const int tb = w << 8;  // wave's t-base (256-range)

  const unsigned short* qsb = qs + ((size_t)bh * S_ + sblk * 32) * DK_;
  const unsigned short* ksb = ks + (size_t)bh * S_ * DK_ + (size_t)tb * DK_;
  const unsigned short* pmw = pm3 +
      ((size_t)((b * 64 + sblk) * 8 + w) * 32) * 256;  // 32 chunks of 256 u16
  const unsigned short* vtb = vsT + (size_t)b * DK_ * S_ + tb;

  // Q fragments for both row-sets
  bf16x8 aq0[2], aq1[2];
#pragma unroll
  for (int kss = 0; kss < 2; ++kss) {
    aq0[kss] = *(const bf16x8*)(qsb + (size_t)l4 * DK_ + (kss * 4 + g) * 8);
    aq1[kss] = *(const bf16x8*)(qsb + (size_t)(16 + l4) * DK_ + (kss * 4 + g) * 8);
  }

  char* pbase = (char*)&lds_p[w][0];  // 16 KB, row r at byte r*512
  const int swz = (l4 & 7) << 4;      // XOR byte bits 4..6 ((row&7)==(l4&7))

  // ---------- PHASE 1: 4 tiles of 64 t; QK(x2) + blend -> p in LDS ----------
  float lsum0 = 0.f, lsum1 = 0.f;
  u16x4 pc0[2][4], pc1[2][4];   // pm chunks, 2-deep ring
#pragma unroll
  for (int d = 0; d < 2; ++d)
#pragma unroll
    for (int ct = 0; ct < 4; ++ct) {
      pc0[d][ct] = *(const u16x4*)(pmw + (size_t)((d * 4 + ct) * 2 + 0) * 256 + lane * 4);
      pc1[d][ct] = *(const u16x4*)(pmw + (size_t)((d * 4 + ct) * 2 + 1) * 256 + lane * 4);
    }
  bf16x8 kf[2][4][2];           // K, 1-deep ring
#pragma unroll
  for (int ct = 0; ct < 4; ++ct)
#pragma unroll
    for (int kss = 0; kss < 2; ++kss)
      kf[0][ct][kss] = *(const bf16x8*)(ksb +
          (size_t)(ct * 16 + l4) * DK_ + (kss * 4 + g) * 8);

#pragma unroll
  for (int i = 0; i < 4; ++i) {
    const int tr = i * 64;
    const int cur = i & 1, nxt = (i + 1) & 1;
    if (i + 1 < 4) {
#pragma unroll
      for (int ct = 0; ct < 4; ++ct)
#pragma unroll
        for (int kss = 0; kss < 2; ++kss)
          kf[nxt][ct][kss] = *(const bf16x8*)(ksb +
              (size_t)((i + 1) * 64 + ct * 16 + l4) * DK_ + (kss * 4 + g) * 8);
    }
#pragma unroll
    for (int ct = 0; ct < 4; ++ct) {
      f32x4 a0 = {0.f, 0.f, 0.f, 0.f}, a1 = {0.f, 0.f, 0.f, 0.f};
#pragma unroll
      for (int kss = 0; kss < 2; ++kss) {
        a0 = mfma_bf16(kf[cur][ct][kss], aq0[kss], a0);
        a1 = mfma_bf16(kf[cur][ct][kss], aq1[kss], a1);
      }
      u16x4 pb0, pb1;
#pragma unroll
      for (int r = 0; r < 4; ++r) {
        {
          float pmv = bf2f(pc0[cur][ct][r]);
          float sc2 = a0[r] * C1_;
          float e = __builtin_amdgcn_exp2f(-(sc2 + pmv));
          float z = __builtin_amdgcn_rcpf(1.f + e);
          float p = __builtin_amdgcn_exp2f(pmv + z * (sc2 - pmv) - M2_);
          lsum0 += p;
          pb0[r] = f2bf(p);
        }
        {
          float pmv = bf2f(pc1[cur][ct][r]);
          float sc2 = a1[r] * C1_;
          float e = __builtin_amdgcn_exp2f(-(sc2 + pmv));
          float z = __builtin_amdgcn_rcpf(1.f + e);
          float p = __builtin_amdgcn_exp2f(pmv + z * (sc2 - pmv) - M2_);
          lsum1 += p;
          pb1[r] = f2bf(p);
        }
      }
      const int toff = ((tr + ct * 16 + g * 4) * 2) ^ swz;
      *(u16x4*)(pbase + (size_t)l4 * 512 + toff) = pb0;
      *(u16x4*)(pbase + (size_t)(16 + l4) * 512 + toff) = pb1;
    }
    if (i + 2 < 4) {
#pragma unroll
      for (int ct = 0; ct < 4; ++ct) {
        pc0[cur][ct] = *(const u16x4*)(pmw + (size_t)(((i + 2) * 4 + ct) * 2 + 0) * 256 + lane * 4);
        pc1[cur][ct] = *(const u16x4*)(pmw + (size_t)(((i + 2) * 4 + ct) * 2 + 1) * 256 + lane * 4);
      }
    }
  }
  lsum0 += __shfl_xor(lsum0, 16);
  lsum0 += __shfl_xor(lsum0, 32);
  lsum1 += __shfl_xor(lsum1, 16);
  lsum1 += __shfl_xor(lsum1, 32);
  if (g == 0) {
    lds_sum[w][l4] = lsum0;
    lds_sum[w][16 + l4] = lsum1;
  }

  __syncthreads();

  // ---------- PHASE 2: attn stores + PV (both row-sets per V fragment) -----
  float invl0, invl1;
  {
    float s0 = 0.f, s1 = 0.f;
#pragma unroll
    for (int wv = 0; wv < 8; ++wv) {
      s0 += lds_sum[wv][l4];
      s1 += lds_sum[wv][16 + l4];
    }
    invl0 = 1.f / s0;
    invl1 = 1.f / s1;
  }

  f32x4 acc0_[4], acc1_[4];
#pragma unroll
  for (int ni = 0; ni < 4; ++ni) {
    acc0_[ni] = {0.f, 0.f, 0.f, 0.f};
    acc1_[ni] = {0.f, 0.f, 0.f, 0.f};
  }

  float* attrow0 = attn_out +
      (((size_t)b * S_ + sblk * 32 + l4) * H_ + h) * S_ + tb;
  float* attrow1 = attrow0 + (size_t)16 * H_ * S_;

  bf16x8 vf[2][4];  // V, 1-step ring
#pragma unroll
  for (int ni = 0; ni < 4; ++ni)
    vf[0][ni] = *(const bf16x8*)(vtb + (size_t)(ni * 16 + l4) * S_ + g * 8);

#pragma unroll
  for (int st = 0; st < 8; ++st) {
    const int t0 = st * 32;
    const int cur = st & 1, nxt = (st + 1) & 1;
    if (st + 1 < 8) {
#pragma unroll
      for (int ni = 0; ni < 4; ++ni)
        vf[nxt][ni] = *(const bf16x8*)(vtb +
            (size_t)(ni * 16 + l4) * S_ + t0 + 32 + g * 8);
    }
    const int toff = ((t0 + g * 8) * 2) ^ swz;
    bf16x8 pa0 = *(const bf16x8*)(pbase + (size_t)l4 * 512 + toff);
    bf16x8 pa1 = *(const bf16x8*)(pbase + (size_t)(16 + l4) * 512 + toff);
    f32x4 a0, a1, a2, a3;
#pragma unroll
    for (int j = 0; j < 4; ++j) {
      a0[j] = (float)pa0[j] * invl0;
      a1[j] = (float)pa0[4 + j] * invl0;
      a2[j] = (float)pa1[j] * invl1;
      a3[j] = (float)pa1[4 + j] * invl1;
    }
    *(f32x4*)(attrow0 + t0 + g * 8) = a0;
    *(f32x4*)(attrow0 + t0 + g * 8 + 4) = a1;
    *(f32x4*)(attrow1 + t0 + g * 8) = a2;
    *(f32x4*)(attrow1 + t0 + g * 8 + 4) = a3;
#pragma unroll
    for (int ni = 0; ni < 4; ++ni) {
      acc0_[ni] = mfma_bf16(pa0, vf[cur][ni], acc0_[ni]);
      acc1_[ni] = mfma_bf16(pa1, vf[cur][ni], acc1_[ni]);
    }
  }

  // raw PV partials into own (now dead) p region: [row][kk ni*16+l4] f32
  float* pr_lds = (float*)pbase;
#pragma unroll
  for (int ni = 0; ni < 4; ++ni)
#pragma unroll
    for (int r = 0; r < 4; ++r) {
      pr_lds[(g * 4 + r) * 64 + ni * 16 + l4] = acc0_[ni][r];
      pr_lds[(16 + g * 4 + r) * 64 + ni * 16 + l4] = acc1_[ni][r];
    }

  __syncthreads();

  // 8-way reduce + per-row iv; coalesced heads write (512 thr x f32x4)
  {
    int row = tid >> 4;  // element e = tid*4 -> row = e/64, rows 0..31
    float sv = 0.f;
#pragma unroll
    for (int wv = 0; wv < 8; ++wv) sv += lds_sum[wv][row];
    float iv = 1.f / sv;
    f32x4 s4 = {0.f, 0.f, 0.f, 0.f};
#pragma unroll
    for (int wv = 0; wv < 8; ++wv) {
      f32x4 part = *(const f32x4*)((char*)&lds_p[wv][0] + tid * 16);
      s4[0] += part[0]; s4[1] += part[1]; s4[2] += part[2]; s4[3] += part[3];
    }
    s4[0] *= iv; s4[1] *= iv; s4[2] *= iv; s4[3] *= iv;
    *(f32x4*)(heads + ((size_t)bh * S_ + sblk * 32) * 64 + tid * 4) = s4;
  }
}

// ---------------- launch ----------------

extern "C" void kernel_launch(void* const* d_in, const int* in_sizes, int n_in,
                              void* d_out, int out_size, void* d_ws, size_t ws_size,
                              hipStream_t stream) {
  (void)in_sizes; (void)n_in; (void)out_size; (void)ws_size;
  const float* q     = (const float*)d_in[0];
  const float* k     = (const float*)d_in[1];
  const float* v     = (const float*)d_in[2];
  const int*   mask  = (const int*)d_in[3];
  const float* prior = (const float*)d_in[4];
  const float* Wq    = (const float*)d_in[5];
  const float* bq    = (const float*)d_in[6];
  const float* Wk    = (const float*)d_in[7];
  const float* bk    = (const float*)d_in[8];
  const float* Wv    = (const float*)d_in[9];
  const float* bv    = (const float*)d_in[10];
  const float* Wh    = (const float*)d_in[11];

  float* out  = (float*)d_out;
  float* attn = out + (size_t)4096 * 1024;

  char* ws = (char*)d_ws;
  // region [0, 25.2MB): q_bf/k_bf/v_bf during converts+gemms, then pm3 (16.7MB)
  unsigned short* q_bf  = (unsigned short*)(ws + 0);          // 3x 8MB
  unsigned short* pm3   = (unsigned short*)(ws + 0);          // 16.7MB (after gemms)
  float*          heads = (float*)(ws + 33554432);            // 16.7MB
  unsigned short* WqT   = (unsigned short*)(ws + 50331648);   // 4MB (Wq+Wk)
  unsigned short* WvT   = (unsigned short*)(ws + 54525952);   // 128KB
  unsigned short* WhT   = (unsigned short*)(ws + 54657024);   // 128KB
  unsigned short* qs_bf = (unsigned short*)(ws + 54788096);   // 8MB
  unsigned short* ks_bf = (unsigned short*)(ws + 63176704);   // 8MB
  unsigned short* vsT   = (unsigned short*)(ws + 71565312);   // 512KB
  unsigned short* hbar  = (unsigned short*)(ws + 72089600);   // 512KB

  qkv_to_bf16<<<12288, 256, 0, stream>>>(q, k, v, q_bf);
  pack_wqk2<<<8192, 256, 0, stream>>>(Wq, Wk, WqT);
  pack_wv<<<256, 256, 0, stream>>>(Wv, WvT);
  pack_wh<<<256, 256, 0, stream>>>(Wh, WhT);

  gemm_bt<128, 0><<<dim3(32, 8), 256, 0, stream>>>(q_bf, WqT, bq, qs_bf, 4096, 1024, 1024);
  gemm_bt<128, 0><<<dim3(32, 8), 256, 0, stream>>>(q_bf + 4194304, WqT + 1048576, bk, ks_bf, 4096, 1024, 1024);
  gemm_bt<64, 1><<<dim3(32, 1), 256, 0, stream>>>(q_bf + 8388608, WvT, bv, vsT, 4096, 64, 1024);

  make_pm3<<<8192, 256, 0, stream>>>(mask, prior, pm3);

  attn_fused1<<<2048, 512, 0, stream>>>(qs_bf, ks_bf, vsT, pm3, attn, heads);

  mean_heads<<<1024, 256, 0, stream>>>(heads, hbar);
  gemm_bt<128, 2><<<dim3(32, 8), 256, 0, stream>>>(hbar, WhT, nullptr, out, 4096, 1024, 64);
}